// Round 1
// baseline (14644.617 us; speedup 1.0000x reference)
//
#include <hip/hip_runtime.h>

// QLSTMGen: T=512 steps of LSTM -> phase -> fe -> GRU on [B=256, H=512].
// Folding: M1 = phase @ fe_W^T;  W2 = [M1 | M1@Wrz^T | M1@Win^T | M1@Whn^T] (512x2560)
//          W1 = [Wih_x | Wih_h + Whh] (2048x768), biases folded.
// Per step: S1 gates=[x|hx]@W1^T -> LSTM elemwise -> h1 ; S2 h1@W2^T -> GRU elemwise -> hx.
// bf16 MFMA 16x16x32, f32 accum; cx kept f32. ws usage ~7.9 MB.

#define T_ 512
#define B_ 256
#define D_ 256
#define H_ 512

typedef short v8s __attribute__((ext_vector_type(8)));
typedef float v4f __attribute__((ext_vector_type(4)));

__device__ __forceinline__ unsigned short f2bf(float f) {
  unsigned u = __float_as_uint(f);
  u = u + 0x7FFFu + ((u >> 16) & 1u);   // RNE
  return (unsigned short)(u >> 16);
}

__device__ __forceinline__ float sigf(float x) {
  return 1.0f / (1.0f + __expf(-x));
}

// ---------------- setup kernels ----------------

// W1[n][k] (2048x768 bf16): k<256 -> Wih_x ; k>=256 -> Wih_h + Whh. b1 = bih+bhh.
__global__ __launch_bounds__(256) void k_setup_w1(
    const float* __restrict__ Wih, const float* __restrict__ Whh,
    const float* __restrict__ bih, const float* __restrict__ bhh,
    unsigned short* __restrict__ W1, float* __restrict__ b1)
{
  int idx = blockIdx.x * 256 + threadIdx.x;
  if (idx < 2048 * 768) {
    int n = idx / 768;
    int k = idx - n * 768;
    float v = Wih[idx];
    if (k >= 256) v += Whh[n * 512 + (k - 256)];
    W1[idx] = f2bf(v);
  }
  if (idx < 2048) b1[idx] = bih[idx] + bhh[idx];
}

// M1f[k][n] = sum_j phase[k][j] * feW[n][j]   (512x512 f32)
__global__ __launch_bounds__(256) void k_m1(
    const float* __restrict__ phase, const float* __restrict__ feW,
    float* __restrict__ M1f)
{
  int idx = blockIdx.x * 256 + threadIdx.x;   // 262144
  int k = idx >> 9, n = idx & 511;
  const float* pr = phase + k * 512;
  const float* fr = feW + n * 512;
  float s = 0.f;
  #pragma unroll 8
  for (int j = 0; j < 512; ++j) s += pr[j] * fr[j];
  M1f[idx] = s;
}

// W2[n'][k] (2560x512 bf16):
//  n'<512          : M1f[k][n']                       (h3)
//  512<=n'<1536    : sum_n M1f[k][n]*(gWih[c]+gWhh[c])  c=n'-512   (r then z)
//  1536<=n'<2048   : sum_n M1f[k][n]*gWih[1024+c]        c=n'-1536 (inn)
//  2048<=n'<2560   : sum_n M1f[k][n]*gWhh[1024+c]        c=n'-2048 (hn)
__global__ __launch_bounds__(256) void k_setup_w2(
    const float* __restrict__ M1f, const float* __restrict__ gWih,
    const float* __restrict__ gWhh, unsigned short* __restrict__ W2)
{
  int idx = blockIdx.x * 256 + threadIdx.x;
  if (idx >= 2560 * 512) return;
  int np = idx >> 9;
  int k  = idx & 511;
  const float* m1k = M1f + k * 512;
  float s = 0.f;
  if (np < 512) {
    s = m1k[np];
  } else if (np < 1536) {
    int c = np - 512;
    const float* a = gWih + c * 512;
    const float* b = gWhh + c * 512;
    #pragma unroll 8
    for (int n = 0; n < 512; ++n) s += m1k[n] * (a[n] + b[n]);
  } else if (np < 2048) {
    int c = np - 1536 + 1024;
    const float* a = gWih + c * 512;
    #pragma unroll 8
    for (int n = 0; n < 512; ++n) s += m1k[n] * a[n];
  } else {
    int c = np - 2048 + 1024;
    const float* b = gWhh + c * 512;
    #pragma unroll 8
    for (int n = 0; n < 512; ++n) s += m1k[n] * b[n];
  }
  W2[idx] = f2bf(s);
}

// bias2[n'] with fe_b folded through the GRU weights.
__global__ __launch_bounds__(256) void k_setup_bias2(
    const float* __restrict__ feb, const float* __restrict__ gWih,
    const float* __restrict__ gWhh, const float* __restrict__ gbih,
    const float* __restrict__ gbhh, float* __restrict__ bias2)
{
  int np = blockIdx.x * 256 + threadIdx.x;
  if (np >= 2560) return;
  float s;
  if (np < 512) {
    s = feb[np];
  } else if (np < 1536) {
    int c = np - 512;
    s = gbih[c] + gbhh[c];
    for (int n = 0; n < 512; ++n) s += feb[n] * (gWih[c * 512 + n] + gWhh[c * 512 + n]);
  } else if (np < 2048) {
    int c = np - 1536 + 1024;
    s = gbih[c];
    for (int n = 0; n < 512; ++n) s += feb[n] * gWih[c * 512 + n];
  } else {
    int c = np - 2048 + 1024;
    s = gbhh[c];
    for (int n = 0; n < 512; ++n) s += feb[n] * gWhh[c * 512 + n];
  }
  bias2[np] = s;
}

__global__ __launch_bounds__(256) void k_init(
    unsigned short* __restrict__ hx, float* __restrict__ cx)
{
  int i = blockIdx.x * 256 + threadIdx.x;
  if (i < B_ * H_) { hx[i] = 0; cx[i] = 0.f; }
}

// ---------------- per-step stage kernels ----------------

// S1: gates[256][2048] = [x_t | hx] @ W1^T + b1 -> LSTM elemwise -> h1, cx.
// Grid 256 = 8 m-tiles x 32 j-tiles; block 256 thr; wave w owns gate w (i,f,g,o),
// 16 j-cols, 32 m-rows (two 16x16 MFMA tiles). K=768 in 24 chunks of 32.
__global__ __launch_bounds__(256) void k_stage1(
    const float* __restrict__ xt,          // [256][256] f32
    const unsigned short* __restrict__ hx, // [256][512] bf16
    const unsigned short* __restrict__ W1, // [2048][768] bf16 (N-major)
    const float* __restrict__ b1,          // [2048]
    float* __restrict__ cx,                // [256][512] f32
    unsigned short* __restrict__ h1)       // [256][512] bf16
{
  __shared__ float lds[4][32][17];
  int blk = blockIdx.x;
  int mt = blk >> 5, jt = blk & 31;
  int m0 = mt << 5, j0 = jt << 4;
  int tid = threadIdx.x;
  int w = tid >> 6;
  int lane = tid & 63;
  int l15 = lane & 15;
  int quad = lane >> 4;

  v4f acc0 = {0.f, 0.f, 0.f, 0.f}, acc1 = {0.f, 0.f, 0.f, 0.f};
  const unsigned short* Bp = W1 + (size_t)((w << 9) + j0 + l15) * 768 + (quad << 3);
  const float* xp0 = xt + (m0 + l15) * 256 + (quad << 3);
  const unsigned short* hp0 = hx + (m0 + l15) * 512 + (quad << 3);

  #pragma unroll 4
  for (int kc = 0; kc < 24; ++kc) {
    v8s bfrag = *(const v8s*)(Bp + kc * 32);
    v8s a0, a1;
    if (kc < 8) {                       // x part (f32 -> bf16 on the fly)
      const float* p0 = xp0 + kc * 32;
      const float* p1 = p0 + 16 * 256;
      #pragma unroll
      for (int i = 0; i < 8; ++i) {
        a0[i] = (short)f2bf(p0[i]);
        a1[i] = (short)f2bf(p1[i]);
      }
    } else {                            // hx part (bf16 direct)
      const unsigned short* q0 = hp0 + (kc - 8) * 32;
      a0 = *(const v8s*)q0;
      a1 = *(const v8s*)(q0 + 16 * 512);
    }
    acc0 = __builtin_amdgcn_mfma_f32_16x16x32_bf16(a0, bfrag, acc0, 0, 0, 0);
    acc1 = __builtin_amdgcn_mfma_f32_16x16x32_bf16(a1, bfrag, acc1, 0, 0, 0);
  }
  #pragma unroll
  for (int r = 0; r < 4; ++r) {
    int m = (quad << 2) + r;            // C/D: row = quad*4+reg, col = lane&15
    lds[w][m][l15] = acc0[r];
    lds[w][m + 16][l15] = acc1[r];
  }
  __syncthreads();
  #pragma unroll
  for (int p = tid; p < 512; p += 256) {
    int m = p >> 4, j = p & 15;
    int jg = j0 + j;
    int b = m0 + m;
    float iv = sigf(lds[0][m][j] + b1[jg]);
    float fv = sigf(lds[1][m][j] + b1[512 + jg]);
    float gv = tanhf(lds[2][m][j] + b1[1024 + jg]);
    float ov = sigf(lds[3][m][j] + b1[1536 + jg]);
    int o = b * 512 + jg;
    float c = fv * cx[o] + iv * gv;
    cx[o] = c;
    h1[o] = f2bf(ov * tanhf(c));
  }
}

// S2: [h3|r|z|inn|hn][256][512 each] = h1 @ W2^T + bias2 -> GRU elemwise -> hx, out.
// Grid 256 = 8 m-tiles x 32 j-tiles. 10 MFMA tiles (5 groups x 2 m-halves);
// waves 0/1 own groups {0,2,4} (m-half = w), waves 2/3 own {1,3} (+redundant g4, unwritten).
__global__ __launch_bounds__(256) void k_stage2(
    const unsigned short* __restrict__ h1, // [256][512] bf16
    const unsigned short* __restrict__ W2, // [2560][512] bf16 (N-major)
    const float* __restrict__ bias2,       // [2560]
    unsigned short* __restrict__ hx,       // [256][512] bf16 (state out)
    float* __restrict__ out_t)             // [256][512] f32
{
  __shared__ float lds[5][32][17];
  int blk = blockIdx.x;
  int mt = blk >> 5, jt = blk & 31;
  int m0 = mt << 5, j0 = jt << 4;
  int tid = threadIdx.x;
  int w = tid >> 6, lane = tid & 63, l15 = lane & 15, quad = lane >> 4;
  int mh = w & 1;
  int ga = w >> 1;            // 0 (waves 0,1) or 1 (waves 2,3)
  int gb = ga + 2;            // 2 or 3

  const unsigned short* Ap = h1 + (size_t)(m0 + (mh << 4) + l15) * 512 + (quad << 3);
  const unsigned short* Ba = W2 + (size_t)((ga << 9) + j0 + l15) * 512 + (quad << 3);
  const unsigned short* Bb = W2 + (size_t)((gb << 9) + j0 + l15) * 512 + (quad << 3);
  const unsigned short* Bc = W2 + (size_t)((4  << 9) + j0 + l15) * 512 + (quad << 3);

  v4f acca = {0.f,0.f,0.f,0.f}, accb = {0.f,0.f,0.f,0.f}, accc = {0.f,0.f,0.f,0.f};
  #pragma unroll 4
  for (int kc = 0; kc < 16; ++kc) {
    v8s a = *(const v8s*)(Ap + kc * 32);
    acca = __builtin_amdgcn_mfma_f32_16x16x32_bf16(a, *(const v8s*)(Ba + kc * 32), acca, 0, 0, 0);
    accb = __builtin_amdgcn_mfma_f32_16x16x32_bf16(a, *(const v8s*)(Bb + kc * 32), accb, 0, 0, 0);
    accc = __builtin_amdgcn_mfma_f32_16x16x32_bf16(a, *(const v8s*)(Bc + kc * 32), accc, 0, 0, 0);
  }
  int mbase = (mh << 4) + (quad << 2);
  #pragma unroll
  for (int r = 0; r < 4; ++r) {
    lds[ga][mbase + r][l15] = acca[r];
    lds[gb][mbase + r][l15] = accb[r];
  }
  if (w < 2) {
    #pragma unroll
    for (int r = 0; r < 4; ++r) lds[4][mbase + r][l15] = accc[r];
  }
  __syncthreads();
  #pragma unroll
  for (int p = tid; p < 512; p += 256) {
    int m = p >> 4, j = p & 15;
    int jg = j0 + j, b = m0 + m;
    float h3 = lds[0][m][j] + bias2[jg];
    float rv = sigf(lds[1][m][j] + bias2[512 + jg]);
    float zv = sigf(lds[2][m][j] + bias2[1024 + jg]);
    float nv = tanhf(lds[3][m][j] + bias2[1536 + jg] + rv * (lds[4][m][j] + bias2[2048 + jg]));
    float hnew = (1.f - zv) * nv + zv * h3;
    int o = b * 512 + jg;
    hx[o] = f2bf(hnew);
    out_t[o] = hnew;
  }
}

// copy final hx (= outputs[T-1]) and cx into the output tail
__global__ __launch_bounds__(256) void k_final(
    float* __restrict__ out, const float* __restrict__ cx)
{
  int i = blockIdx.x * 256 + threadIdx.x;
  if (i < B_ * H_) {
    out[67108864 + i] = out[66977792 + i];          // hx = outputs[511]
    out[67108864 + 131072 + i] = cx[i];             // cx
  }
}

// ---------------- launcher ----------------

extern "C" void kernel_launch(void* const* d_in, const int* in_sizes, int n_in,
                              void* d_out, int out_size, void* d_ws, size_t ws_size,
                              hipStream_t stream)
{
  const float* x     = (const float*)d_in[0];
  const float* Wih   = (const float*)d_in[1];
  const float* Whh   = (const float*)d_in[2];
  const float* bih   = (const float*)d_in[3];
  const float* bhh   = (const float*)d_in[4];
  const float* phase = (const float*)d_in[5];
  const float* feW   = (const float*)d_in[6];
  const float* feb   = (const float*)d_in[7];
  const float* gWih  = (const float*)d_in[8];
  const float* gWhh  = (const float*)d_in[9];
  const float* gbih  = (const float*)d_in[10];
  const float* gbhh  = (const float*)d_in[11];

  char* p = (char*)d_ws;
  unsigned short* W1 = (unsigned short*)p; p += (size_t)2048 * 768 * 2;  // 3 MB
  unsigned short* W2 = (unsigned short*)p; p += (size_t)2560 * 512 * 2;  // 2.5 MB
  float* b1    = (float*)p; p += 2048 * 4;
  float* bias2 = (float*)p; p += 2560 * 4;
  float* M1f   = (float*)p; p += (size_t)512 * 512 * 4;                  // 1 MB
  unsigned short* hx = (unsigned short*)p; p += (size_t)B_ * H_ * 2;
  unsigned short* h1 = (unsigned short*)p; p += (size_t)B_ * H_ * 2;
  float* cx    = (float*)p; p += (size_t)B_ * H_ * 4;

  k_setup_w1<<<6144, 256, 0, stream>>>(Wih, Whh, bih, bhh, W1, b1);
  k_m1<<<1024, 256, 0, stream>>>(phase, feW, M1f);
  k_setup_w2<<<5120, 256, 0, stream>>>(M1f, gWih, gWhh, W2);
  k_setup_bias2<<<10, 256, 0, stream>>>(feb, gWih, gWhh, gbih, gbhh, bias2);
  k_init<<<512, 256, 0, stream>>>(hx, cx);

  float* out = (float*)d_out;
  for (int t = 0; t < T_; ++t) {
    k_stage1<<<256, 256, 0, stream>>>(x + (size_t)t * (B_ * D_), hx, W1, b1, cx, h1);
    k_stage2<<<256, 256, 0, stream>>>(h1, W2, bias2, hx, out + (size_t)t * (B_ * H_));
  }
  k_final<<<512, 256, 0, stream>>>(out, cx);
}